// Round 1
// 452.909 us; speedup vs baseline: 1.1370x; 1.1370x over previous
//
#include <hip/hip_runtime.h>
#include <math.h>

// MultiHeadAttention: B=2, S=2048, D=2048, H=16, dh=128, causal.
// v4: GEMMs replaced with the 256x256 8-phase counted-vmcnt template
// (T2 lds-xor-swizzle + T3/T4 phase pipeline + T5 setprio). Attention,
// rope, transpose, casts unchanged from v3.

typedef _Float16 half8 __attribute__((ext_vector_type(8)));
typedef _Float16 half4v __attribute__((ext_vector_type(4)));
typedef float f32x4 __attribute__((ext_vector_type(4)));

__device__ __forceinline__ void gl_lds16(const void* g, void* l) {
  __builtin_amdgcn_global_load_lds(
      (const __attribute__((address_space(1))) unsigned int*)g,
      (__attribute__((address_space(3))) unsigned int*)l, 16, 0, 0);
}

// ---------------- cast fp32 -> fp16 ----------------
__global__ void cast_f32_f16(const float* __restrict__ src, _Float16* __restrict__ dst, int n4) {
  int i = blockIdx.x * blockDim.x + threadIdx.x;
  if (i >= n4) return;
  float4 v = reinterpret_cast<const float4*>(src)[i];
  half4v o;
  o[0] = (_Float16)v.x; o[1] = (_Float16)v.y; o[2] = (_Float16)v.z; o[3] = (_Float16)v.w;
  reinterpret_cast<half4v*>(dst)[i] = o;
}

__global__ void cast_w(const float* __restrict__ w0, const float* __restrict__ w1,
                       const float* __restrict__ w2, const float* __restrict__ w3,
                       _Float16* __restrict__ wdst) {
  const float* s = blockIdx.y == 0 ? w0 : blockIdx.y == 1 ? w1 : blockIdx.y == 2 ? w2 : w3;
  int i = blockIdx.x * blockDim.x + threadIdx.x;  // < 1048576 float4 groups
  float4 v = reinterpret_cast<const float4*>(s)[i];
  half4v o;
  o[0] = (_Float16)v.x; o[1] = (_Float16)v.y; o[2] = (_Float16)v.z; o[3] = (_Float16)v.w;
  reinterpret_cast<half4v*>(wdst)[(size_t)blockIdx.y * 1048576 + i] = o;
}

// ---------------- GEMM: C[M,N] = A[M,K] * B[N,K]^T + bias ----------------
// 256x256 tile, BK=64, 512 threads = 8 waves (2M x 4N), wave tile 128x64.
// 8-phase schedule (4 phases per K-tile, 2 K-tiles per dbuf cycle):
//   each phase: {ds_read subtile | issue half-tile global_load_lds} ->
//               barrier -> setprio(1) 16xMFMA setprio(0) -> [vmcnt ckpt] -> barrier
// LDS: linear dest for global_load_lds; XOR swizzle (slot ^= row&7) applied to
// the GLOBAL source and again on ds_read (rule #21: both-sides involution).
//
// Stage schedule for K-tile t+1's four 128x64 half-tiles (2 loads each):
//   H1 = A-half0 issued at P4(t-1); H2 = A-half1 at P1(t);
//   H3 = B-half0 at P2(t);          H4 = B-half1 at P3(t).
// Single checkpoint at end of P4(t): queue = [H1..H4 of t+1, H1 of t+2]
// (10 loads) -> s_waitcnt vmcnt(2) retires all of tile t+1, leaves H1 of
// t+2 in flight. Never drains to 0 until the last two tiles (epilogue).
// WAR: stages into buf of t+1 (= buf of t-1) start at P4(t-1), after all
// reads of tile t-1 completed (each phase's ds_reads are consumed by that
// phase's MFMAs before its trailing barrier).
template <bool OUT_F32>
__global__ __launch_bounds__(512, 2) void gemm_bt256(
    const _Float16* __restrict__ A,   // M x K
    const _Float16* __restrict__ B,   // N x K
    const float* __restrict__ b0, const float* __restrict__ b1,
    const float* __restrict__ b2,     // bias for col/2048 == 0,1,2
    void* __restrict__ Cout,          // M x N
    int M, int N, int K) {
  __shared__ _Float16 As[2][16384];  // 2 x 256x64, 64 KB
  __shared__ _Float16 Bs[2][16384];  // 64 KB
  const int bm = blockIdx.y * 256, bn = blockIdx.x * 256;
  const int tid = threadIdx.x;
  const int wave = tid >> 6, lane = tid & 63;
  const int quad = lane >> 4, l16 = lane & 15;
  const int wm = (wave >> 2) * 128, wn = (wave & 3) * 64;

  // ---- staging geometry: one call = 64 rows x 128B, 512 thr x 16B ----
  // thread covers row (call_base + tid>>3), phys 16B-slot tid&7.
  // phys slot p at row r holds logical slot s = p ^ (r&7)  (r&7 == srow&7).
  const int srow = tid >> 3;
  const int sslot = (tid & 7) ^ (srow & 7);
  const _Float16* Ag = A + (size_t)(bm + srow) * K + sslot * 8;
  const _Float16* Bg = B + (size_t)(bn + srow) * K + sslot * 8;

#define STAGE_A(buf, h, c, kt)                                      \
  gl_lds16(Ag + (size_t)((h) * 128 + (c) * 64) * K + (kt) * 64,     \
           &As[buf][(h) * 8192 + (c) * 4096 + tid * 8])
#define STAGE_B(buf, h, c, kt)                                      \
  gl_lds16(Bg + (size_t)((h) * 128 + (c) * 64) * K + (kt) * 64,     \
           &Bs[buf][(h) * 8192 + (c) * 4096 + tid * 8])

  // ---- fragment-read geometry (swizzled ds_read_b128) ----
  // frag (row16 i, kstep kk): row = base + i*16 + l16, logical slot kk*4+quad,
  // phys slot = (kk*4+quad) ^ (l16&7) -> 2-way max bank aliasing (free).
  const int axor = l16 & 7;
  const int sl0 = ((0 + quad) ^ axor) * 8;
  const int sl1 = ((4 + quad) ^ axor) * 8;
  const int aoff = (wm + l16) * 64;
  const int boff = (wn + l16) * 64;

#define RD_A(i, kk) \
  (*reinterpret_cast<const half8*>(&As[cur][aoff + (i) * 1024 + ((kk) ? sl1 : sl0)]))
#define RD_B(j, kk) \
  (*reinterpret_cast<const half8*>(&Bs[cur][boff + (j) * 1024 + ((kk) ? sl1 : sl0)]))

  f32x4 acc[8][4];
#pragma unroll
  for (int i = 0; i < 8; ++i)
#pragma unroll
    for (int j = 0; j < 4; ++j) acc[i][j] = f32x4{0.f, 0.f, 0.f, 0.f};

  half8 a[4][2], b[4][2];
  const int NT = K >> 6;

  // ---- prologue: tile 0 (all 4 halves) + A-half0 of tile 1 ----
  STAGE_A(0, 0, 0, 0); STAGE_A(0, 0, 1, 0);
  STAGE_A(0, 1, 0, 0); STAGE_A(0, 1, 1, 0);
  STAGE_B(0, 0, 0, 0); STAGE_B(0, 0, 1, 0);
  STAGE_B(0, 1, 0, 0); STAGE_B(0, 1, 1, 0);
  if (NT > 1) {
    STAGE_A(1, 0, 0, 1); STAGE_A(1, 0, 1, 1);
    asm volatile("s_waitcnt vmcnt(2)");
  } else {
    asm volatile("s_waitcnt vmcnt(0)");
  }
  __builtin_amdgcn_s_barrier();

  for (int t = 0; t < NT; ++t) {
    const int cur = t & 1, nxt = cur ^ 1;
    const bool pf = (t + 1 < NT);
    const bool pf2 = (t + 2 < NT);

    // ---- P1: read a[0..3](m-half lo), b[0..1]; stage A-half1(t+1) ----
#pragma unroll
    for (int i = 0; i < 4; ++i) {
      a[i][0] = RD_A(i, 0); a[i][1] = RD_A(i, 1);
    }
#pragma unroll
    for (int j = 0; j < 2; ++j) {
      b[j][0] = RD_B(j, 0); b[j][1] = RD_B(j, 1);
    }
    if (pf) { STAGE_A(nxt, 1, 0, t + 1); STAGE_A(nxt, 1, 1, t + 1); }
    __builtin_amdgcn_s_barrier();
    __builtin_amdgcn_s_setprio(1);
#pragma unroll
    for (int i = 0; i < 4; ++i)
#pragma unroll
      for (int j = 0; j < 2; ++j) {
        acc[i][j] = __builtin_amdgcn_mfma_f32_16x16x32_f16(a[i][0], b[j][0], acc[i][j], 0, 0, 0);
        acc[i][j] = __builtin_amdgcn_mfma_f32_16x16x32_f16(a[i][1], b[j][1], acc[i][j], 0, 0, 0);
      }
    __builtin_amdgcn_s_setprio(0);
    __builtin_amdgcn_s_barrier();

    // ---- P2: read b[2..3]; stage B-half0(t+1); MFMA m-lo x n-hi ----
#pragma unroll
    for (int j = 2; j < 4; ++j) {
      b[j][0] = RD_B(j, 0); b[j][1] = RD_B(j, 1);
    }
    if (pf) { STAGE_B(nxt, 0, 0, t + 1); STAGE_B(nxt, 0, 1, t + 1); }
    __builtin_amdgcn_s_barrier();
    __builtin_amdgcn_s_setprio(1);
#pragma unroll
    for (int i = 0; i < 4; ++i)
#pragma unroll
      for (int j = 2; j < 4; ++j) {
        acc[i][j] = __builtin_amdgcn_mfma_f32_16x16x32_f16(a[i][0], b[j][0], acc[i][j], 0, 0, 0);
        acc[i][j] = __builtin_amdgcn_mfma_f32_16x16x32_f16(a[i][1], b[j][1], acc[i][j], 0, 0, 0);
      }
    __builtin_amdgcn_s_setprio(0);
    __builtin_amdgcn_s_barrier();

    // ---- P3: read a[0..3] <- m-half hi (i=4..7); stage B-half1(t+1) ----
#pragma unroll
    for (int i = 0; i < 4; ++i) {
      a[i][0] = RD_A(i + 4, 0); a[i][1] = RD_A(i + 4, 1);
    }
    if (pf) { STAGE_B(nxt, 1, 0, t + 1); STAGE_B(nxt, 1, 1, t + 1); }
    __builtin_amdgcn_s_barrier();
    __builtin_amdgcn_s_setprio(1);
#pragma unroll
    for (int i = 0; i < 4; ++i)
#pragma unroll
      for (int j = 0; j < 2; ++j) {
        acc[i + 4][j] = __builtin_amdgcn_mfma_f32_16x16x32_f16(a[i][0], b[j][0], acc[i + 4][j], 0, 0, 0);
        acc[i + 4][j] = __builtin_amdgcn_mfma_f32_16x16x32_f16(a[i][1], b[j][1], acc[i + 4][j], 0, 0, 0);
      }
    __builtin_amdgcn_s_setprio(0);
    __builtin_amdgcn_s_barrier();

    // ---- P4: stage A-half0(t+2) into cur; MFMA m-hi x n-hi; checkpoint ----
    if (pf2) { STAGE_A(cur, 0, 0, t + 2); STAGE_A(cur, 0, 1, t + 2); }
    __builtin_amdgcn_s_barrier();
    __builtin_amdgcn_s_setprio(1);
#pragma unroll
    for (int i = 0; i < 4; ++i)
#pragma unroll
      for (int j = 2; j < 4; ++j) {
        acc[i + 4][j] = __builtin_amdgcn_mfma_f32_16x16x32_f16(a[i][0], b[j][0], acc[i + 4][j], 0, 0, 0);
        acc[i + 4][j] = __builtin_amdgcn_mfma_f32_16x16x32_f16(a[i][1], b[j][1], acc[i + 4][j], 0, 0, 0);
      }
    __builtin_amdgcn_s_setprio(0);
    if (pf2)
      asm volatile("s_waitcnt vmcnt(2)");   // retire all of tile t+1; H1(t+2) stays in flight
    else
      asm volatile("s_waitcnt vmcnt(0)");   // epilogue drain (last two tiles)
    __builtin_amdgcn_s_barrier();
  }

  // ---- epilogue: bias + store ----
#pragma unroll
  for (int j = 0; j < 4; ++j) {
    const int gc = bn + wn + j * 16 + l16;
    const float* bp = (gc < 2048) ? b0 : (gc < 4096 ? b1 : b2);
    const float bz = bp[gc & 2047];
#pragma unroll
    for (int i = 0; i < 8; ++i) {
#pragma unroll
      for (int r = 0; r < 4; ++r) {
        const int gr = bm + wm + i * 16 + quad * 4 + r;
        float v = acc[i][j][r] + bz;
        if (OUT_F32)
          reinterpret_cast<float*>(Cout)[(size_t)gr * N + gc] = v;
        else
          reinterpret_cast<_Float16*>(Cout)[(size_t)gr * N + gc] = (_Float16)v;
      }
    }
  }
#undef STAGE_A
#undef STAGE_B
#undef RD_A
#undef RD_B
}

// ---------------- RoPE in-place on fused qkv (rows stride 6144) ----------------
__global__ void rope_inplace(_Float16* __restrict__ qkv, int ngroups) {
  int idx = blockIdx.x * blockDim.x + threadIdx.x;
  if (idx >= ngroups) return;
  int m = idx >> 8;
  int g = idx & 255;
  int s = m & 2047;
  const float scale = 0.088388347648318447f;  // 1/sqrt(128)
  size_t base = (size_t)m * 6144 + g * 8;
  half8 qv = *reinterpret_cast<const half8*>(qkv + base);
  half8 kv = *reinterpret_cast<const half8*>(qkv + base + 2048);
  half8 qo, ko;
#pragma unroll
  for (int j = 0; j < 4; ++j) {
    int i = (g * 4 + j) & 63;
    float ang = (float)s * exp2f(-0.2076205059304601f * (float)i);
    float sn, cs;
    __sincosf(ang, &sn, &cs);
    float e = (float)qv[j * 2], o = (float)qv[j * 2 + 1];
    qo[j * 2]     = (_Float16)((e * cs - o * sn) * scale);
    qo[j * 2 + 1] = (_Float16)((o * cs + e * sn) * scale);
    e = (float)kv[j * 2]; o = (float)kv[j * 2 + 1];
    ko[j * 2]     = (_Float16)(e * cs - o * sn);
    ko[j * 2 + 1] = (_Float16)(o * cs + e * sn);
  }
  *reinterpret_cast<half8*>(qkv + base) = qo;
  *reinterpret_cast<half8*>(qkv + base + 2048) = ko;
}

// ---------------- V transpose: qkv v-cols (stride 6144) -> (B,H,dh,S) ----------------
__global__ __launch_bounds__(256) void transpose_v(const _Float16* __restrict__ qkv,
                                                   _Float16* __restrict__ vt) {
  __shared__ _Float16 t[64][72];
  const int s0 = blockIdx.x * 64;
  const int d0 = blockIdx.y * 64;
  const int bh = blockIdx.z;
  const int b = bh >> 4, h = bh & 15;
  const int tid = threadIdx.x;
#pragma unroll
  for (int p = 0; p < 2; ++p) {
    int chunk = p * 256 + tid;
    int r = chunk >> 3, c8 = (chunk & 7) * 8;
    *reinterpret_cast<half8*>(&t[r][c8]) = *reinterpret_cast<const half8*>(
        &qkv[(size_t)(b * 2048 + s0 + r) * 6144 + 4096 + h * 128 + d0 + c8]);
  }
  __syncthreads();
#pragma unroll
  for (int p = 0; p < 2; ++p) {
    int chunk = p * 256 + tid;
    int dr = chunk >> 3, c8 = (chunk & 7) * 8;
    half8 o;
#pragma unroll
    for (int j = 0; j < 8; ++j) o[j] = t[c8 + j][dr];
    *reinterpret_cast<half8*>(&vt[(size_t)(bh * 128 + d0 + dr) * 2048 + s0 + c8]) = o;
  }
}

// ---------------- Flash attention (causal), dbuf LDS K/V ----------------
__global__ __launch_bounds__(256, 2) void attn_kernel(
    const _Float16* __restrict__ QKV,  // (4096, 6144): q|k|v
    const _Float16* __restrict__ VT,   // (32, 128, 2048)
    _Float16* __restrict__ ctx) {      // (4096, 2048)
  constexpr int LD = 6144, S = 2048;
  __shared__ _Float16 Ks[2][8192];
  __shared__ _Float16 Vs[2][8192];
  __shared__ _Float16 P[4][16][80];
  const int bid = blockIdx.x;
  const int bh = bid & 31;
  const int qt = 31 - (bid >> 5);
  const int b = bh >> 4, h = bh & 15;
  const int tid = threadIdx.x;
  const int wv = tid >> 6, lane = tid & 63;
  const int quad = lane >> 4, l16 = lane & 15;
  const int q0 = qt * 64 + wv * 16;

  const _Float16* qp = QKV + (size_t)(b * S + q0 + l16) * LD + h * 128;
  half8 aq[4];
#pragma unroll
  for (int ks = 0; ks < 4; ++ks)
    aq[ks] = *reinterpret_cast<const half8*>(qp + ks * 32 + quad * 8);

  const _Float16* gk[4];
  const _Float16* gv[4];
  int lofs[4];
#pragma unroll
  for (int p = 0; p < 4; ++p) {
    int c = p * 256 + tid;
    int cl16 = c & 15, cqd = (c >> 4) & 3;
    int cks = (c >> 6) & 3, cf = c >> 8;
    gk[p] = QKV + (size_t)(b * S + cf * 16 + cl16) * LD + 2048 + h * 128 + cks * 32 + cqd * 8;
    int ckv = (c >> 6) & 1, ct = c >> 7;
    gv[p] = VT + (size_t)(bh * 128 + ct * 16 + cl16) * S + ckv * 32 + cqd * 8;
    lofs[p] = c * 8;
  }

  f32x4 acc[8];
#pragma unroll
  for (int t = 0; t < 8; ++t) acc[t] = f32x4{0.f, 0.f, 0.f, 0.f};
  f32x4 lacc = f32x4{0.f, 0.f, 0.f, 0.f};
  float m_i[4];
#pragma unroll
  for (int r = 0; r < 4; ++r) m_i[r] = -INFINITY;

  half8 ones;
#pragma unroll
  for (int j = 0; j < 8; ++j) ones[j] = (_Float16)1.0f;

#pragma unroll
  for (int p = 0; p < 4; ++p) gl_lds16(gk[p], &Ks[0][lofs[p]]);
#pragma unroll
  for (int p = 0; p < 4; ++p) gl_lds16(gv[p], &Vs[0][lofs[p]]);

  for (int j = 0; j <= qt; ++j) {
    __syncthreads();
    const int cur = j & 1;
    if (j < qt) {
      const size_t ko = (size_t)(j + 1) * 64 * LD;
      const int vo = (j + 1) * 64;
#pragma unroll
      for (int p = 0; p < 4; ++p) gl_lds16(gk[p] + ko, &Ks[cur ^ 1][lofs[p]]);
#pragma unroll
      for (int p = 0; p < 4; ++p) gl_lds16(gv[p] + vo, &Vs[cur ^ 1][lofs[p]]);
    }
    f32x4 sf[4];
#pragma unroll
    for (int f = 0; f < 4; ++f) sf[f] = f32x4{0.f, 0.f, 0.f, 0.f};
#pragma unroll
    for (int f = 0; f < 4; ++f)
#pragma unroll
      for (int ks = 0; ks < 4; ++ks) {
        half8 bk = *reinterpret_cast<const half8*>(&Ks[cur][((f * 4 + ks) * 4 + quad) * 128 + l16 * 8]);
        sf[f] = __builtin_amdgcn_mfma_f32_16x16x32_f16(aq[ks], bk, sf[f], 0, 0, 0);
      }
    if (j == qt) {
      const int key0 = j * 64;
#pragma unroll
      for (int f = 0; f < 4; ++f) {
        const int key = key0 + f * 16 + l16;
#pragma unroll
        for (int r = 0; r < 4; ++r) {
          const int row = q0 + quad * 4 + r;
          sf[f][r] = (key <= row) ? sf[f][r] : -1e30f;
        }
      }
    }
    float alpha[4];
#pragma unroll
    for (int r = 0; r < 4; ++r) {
      float tm = fmaxf(fmaxf(sf[0][r], sf[1][r]), fmaxf(sf[2][r], sf[3][r]));
      tm = fmaxf(tm, __shfl_xor(tm, 1));
      tm = fmaxf(tm, __shfl_xor(tm, 2));
      tm = fmaxf(tm, __shfl_xor(tm, 4));
      tm = fmaxf(tm, __shfl_xor(tm, 8));
      const float mn = fmaxf(m_i[r], tm);
      alpha[r] = __expf(m_i[r] - mn);
      m_i[r] = mn;
    }
#pragma unroll
    for (int f = 0; f < 4; ++f)
#pragma unroll
      for (int r = 0; r < 4; ++r)
        P[wv][quad * 4 + r][f * 16 + l16] = (_Float16)__expf(sf[f][r] - m_i[r]);
    half8 pa0 = *reinterpret_cast<const half8*>(&P[wv][l16][quad * 8]);
    half8 pa1 = *reinterpret_cast<const half8*>(&P[wv][l16][32 + quad * 8]);
#pragma unroll
    for (int t = 0; t < 8; ++t)
#pragma unroll
      for (int r = 0; r < 4; ++r) acc[t][r] *= alpha[r];
#pragma unroll
    for (int r = 0; r < 4; ++r) lacc[r] *= alpha[r];
#pragma unroll
    for (int t = 0; t < 8; ++t) {
      half8 bv0 = *reinterpret_cast<const half8*>(&Vs[cur][((t * 2 + 0) * 4 + quad) * 128 + l16 * 8]);
      half8 bv1 = *reinterpret_cast<const half8*>(&Vs[cur][((t * 2 + 1) * 4 + quad) * 128 + l16 * 8]);
      acc[t] = __builtin_amdgcn_mfma_f32_16x16x32_f16(pa0, bv0, acc[t], 0, 0, 0);
      acc[t] = __builtin_amdgcn_mfma_f32_16x16x32_f16(pa1, bv1, acc[t], 0, 0, 0);
    }
    lacc = __builtin_amdgcn_mfma_f32_16x16x32_f16(pa0, ones, lacc, 0, 0, 0);
    lacc = __builtin_amdgcn_mfma_f32_16x16x32_f16(pa1, ones, lacc, 0, 0, 0);
  }

  float inv[4];
#pragma unroll
  for (int r = 0; r < 4; ++r) inv[r] = 1.0f / lacc[r];
#pragma unroll
  for (int t = 0; t < 8; ++t)
#pragma unroll
    for (int r = 0; r < 4; ++r)
      ctx[(size_t)(b * S + q0 + quad * 4 + r) * 2048 + h * 128 + t * 16 + l16] =
          (_Float16)(acc[t][r] * inv[r]);
}

// ---------------- launcher ----------------
extern "C" void kernel_launch(void* const* d_in, const int* in_sizes, int n_in,
                              void* d_out, int out_size, void* d_ws, size_t ws_size,
                              hipStream_t stream) {
  const float* x  = (const float*)d_in[0];
  const float* wq = (const float*)d_in[1];
  const float* bq = (const float*)d_in[2];
  const float* wk = (const float*)d_in[3];
  const float* bk = (const float*)d_in[4];
  const float* wv = (const float*)d_in[5];
  const float* bv = (const float*)d_in[6];
  const float* wo = (const float*)d_in[7];
  const float* bo = (const float*)d_in[8];

  _Float16* W      = (_Float16*)d_ws;
  _Float16* xh     = W;                  // 16 MB (4096,2048)
  _Float16* wqkvh  = xh + 8388608;       // 24 MB (6144,2048) contiguous wq|wk|wv
  _Float16* woh    = wqkvh + 12582912;   // 8 MB  (2048,2048)
  _Float16* qkvlin = woh + 4194304;      // 48 MB (4096,6144)
  _Float16* vT     = xh;                 // reuse: x dead after QKV gemm
  _Float16* ctx    = wqkvh;              // reuse: wqkv dead after QKV gemm

  cast_f32_f16<<<8192, 256, 0, stream>>>(x, xh, 2097152);
  cast_w<<<dim3(4096, 4), 256, 0, stream>>>(wq, wk, wv, wo, wqkvh);

  // fused QKV gemm: (4096,2048) x (6144,2048)^T -> (4096,6144)
  gemm_bt256<false><<<dim3(24, 16), 512, 0, stream>>>(xh, wqkvh, bq, bk, bv, qkvlin,
                                                      4096, 6144, 2048);

  rope_inplace<<<4096, 256, 0, stream>>>(qkvlin, 1048576);
  transpose_v<<<dim3(32, 2, 32), 256, 0, stream>>>(qkvlin, vT);
  attn_kernel<<<1024, 256, 0, stream>>>(qkvlin, vT, ctx);

  // output gemm: (4096,2048) x (2048,2048)^T -> fp32 out
  gemm_bt256<true><<<dim3(8, 16), 512, 0, stream>>>(ctx, woh, bo, bo, bo, (float*)d_out,
                                                    4096, 2048, 2048);
}

// Round 2
// 451.602 us; speedup vs baseline: 1.1403x; 1.0029x over previous
//
#include <hip/hip_runtime.h>
#include <math.h>

// MultiHeadAttention: B=2, S=2048, D=2048, H=16, dh=128, causal.
// v5: GEMM pipeline deepened to the true m201 schedule: stages land 3-6
// phases before their vmcnt(6) checkpoint (was 1 phase in v4). B LDS rows
// permuted (sigma-map) so phase-freed regions are contiguous stage units.

typedef _Float16 half8 __attribute__((ext_vector_type(8)));
typedef _Float16 half4v __attribute__((ext_vector_type(4)));
typedef float f32x4 __attribute__((ext_vector_type(4)));

__device__ __forceinline__ void gl_lds16(const void* g, void* l) {
  __builtin_amdgcn_global_load_lds(
      (const __attribute__((address_space(1))) unsigned int*)g,
      (__attribute__((address_space(3))) unsigned int*)l, 16, 0, 0);
}

// ---------------- cast fp32 -> fp16 ----------------
__global__ void cast_f32_f16(const float* __restrict__ src, _Float16* __restrict__ dst, int n4) {
  int i = blockIdx.x * blockDim.x + threadIdx.x;
  if (i >= n4) return;
  float4 v = reinterpret_cast<const float4*>(src)[i];
  half4v o;
  o[0] = (_Float16)v.x; o[1] = (_Float16)v.y; o[2] = (_Float16)v.z; o[3] = (_Float16)v.w;
  reinterpret_cast<half4v*>(dst)[i] = o;
}

__global__ void cast_w(const float* __restrict__ w0, const float* __restrict__ w1,
                       const float* __restrict__ w2, const float* __restrict__ w3,
                       _Float16* __restrict__ wdst) {
  const float* s = blockIdx.y == 0 ? w0 : blockIdx.y == 1 ? w1 : blockIdx.y == 2 ? w2 : w3;
  int i = blockIdx.x * blockDim.x + threadIdx.x;  // < 1048576 float4 groups
  float4 v = reinterpret_cast<const float4*>(s)[i];
  half4v o;
  o[0] = (_Float16)v.x; o[1] = (_Float16)v.y; o[2] = (_Float16)v.z; o[3] = (_Float16)v.w;
  reinterpret_cast<half4v*>(wdst)[(size_t)blockIdx.y * 1048576 + i] = o;
}

// ---------------- GEMM: C[M,N] = A[M,K] * B[N,K]^T + bias ----------------
// 256x256 tile, BK=64, 512 threads = 8 waves (2M x 4N), wave tile 128x64.
// 4 phases per K-tile; each phase: {ds_read subtile | 2x global_load_lds
// stage} -> barrier -> setprio(1) 16xMFMA setprio(0) -> barrier; one
// vmcnt checkpoint per tile at P4.
//
// LDS row layouts:
//   A: linear rows 0..255 (row r at offset r*64 halfs).
//   B: permuted sigma(r) = ((r>>5)&1)*128 + (r>>6)*32 + (r&31), so that
//      P1's reads (frags j=0,1 over all 4 n-wave-groups) hit sigma 0-127
//      and P2's (j=2,3) hit sigma 128-255 -> contiguous freeable halves.
// XOR swizzle (both-sides involution, rule #21): 16B-slot ^= (ldsrow&7),
// applied on the pre-swizzled GLOBAL source at stage time and on the
// ds_read address. sigma&7 == r&7-free invariants: stage uses srow&7,
// reads use l16&7; both equal (ldsrow&7).
//
// Stage units (2 gl_lds calls each = 64 rows x 128B, one per phase pair):
//   uA0=A[0:64), uA1=A[128:192)   freed by P1   staged at P2(t) for t+2
//   vB0=sig[0:64), vB1=sig[64:128) freed by P1  staged at P3(t) for t+2
//   vB2=sig[128:192), vB3=sig[192:256) freed P2 staged at P4(t) for t+2
//   uA2=A[64:128), uA3=A[192:256)  freed by P3  staged at P1(t) for t+1
// FIFO at P4(t) checkpoint: 6 outstanding (tile t+2 units from P2-P4)
// + 8 of tile t+1 -> vmcnt(6) retires exactly tile t+1. Slack 3-6 phases.
template <bool OUT_F32>
__global__ __launch_bounds__(512, 2) void gemm_bt256(
    const _Float16* __restrict__ A,   // M x K
    const _Float16* __restrict__ B,   // N x K
    const float* __restrict__ b0, const float* __restrict__ b1,
    const float* __restrict__ b2,     // bias for col/2048 == 0,1,2
    void* __restrict__ Cout,          // M x N
    int M, int N, int K) {
  __shared__ _Float16 As[2][16384];  // 2 x 256x64, 64 KB
  __shared__ _Float16 Bs[2][16384];  // 64 KB (sigma-permuted rows)
  const int bm = blockIdx.y * 256, bn = blockIdx.x * 256;
  const int tid = threadIdx.x;
  const int wave = tid >> 6, lane = tid & 63;
  const int quad = lane >> 4, l16 = lane & 15;
  const int wm = (wave >> 2) * 128, wn = (wave & 3) * 64;

  // ---- staging geometry ----
  const int srow = tid >> 3;                 // 0..63 within a 64-row unit
  const int sx = (tid & 7) ^ (srow & 7);     // pre-swizzled logical 16B slot
  const _Float16* Ag = A + (size_t)(bm + srow) * K + sx * 8;
  // B stage bases per unit c: global row r(c,srow) for sigma-row c*64+srow
  const _Float16* Bg[4];
#pragma unroll
  for (int c = 0; c < 4; ++c) {
    int r = (((c * 2 + (srow >> 5)) & 3) << 6) + ((c >> 1) << 5) + (srow & 31);
    Bg[c] = B + (size_t)(bn + r) * K + sx * 8;
  }

#define STAGE_A(buf, R, kt) \
  gl_lds16(Ag + (size_t)(R) * K + (kt) * 64, &As[buf][(R) * 64 + tid * 8])
#define STAGE_B(buf, c, kt) \
  gl_lds16(Bg[c] + (kt) * 64, &Bs[buf][(c) * 4096 + tid * 8])

  // ---- fragment-read geometry (swizzled ds_read_b128) ----
  const int axor = l16 & 7;
  const int sl0 = ((0 + quad) ^ axor) * 8;   // kk=0 logical slot quad
  const int sl1 = ((4 + quad) ^ axor) * 8;   // kk=1
  const int aoff = (wm + l16) * 64;
  const int q4 = (wn >> 6) * 32;             // B sigma q-stripe

#define RD_A(i, kk) \
  (*reinterpret_cast<const half8*>(&As[cur][aoff + (i) * 1024 + ((kk) ? sl1 : sl0)]))
#define RD_B(j, kk) \
  (*reinterpret_cast<const half8*>( \
      &Bs[cur][((((j) >> 1) * 128 + q4 + ((j) & 1) * 16 + l16)) * 64 + ((kk) ? sl1 : sl0)]))

  f32x4 acc[8][4];
#pragma unroll
  for (int i = 0; i < 8; ++i)
#pragma unroll
    for (int j = 0; j < 4; ++j) acc[i][j] = f32x4{0.f, 0.f, 0.f, 0.f};

  half8 a[4][2], b[4][2];
  const int NT = K >> 6;

  // ---- prologue: tile0 fully (8 units, buf0); tile1 minus uA2/uA3 (buf1) ----
  STAGE_A(0, 0, 0); STAGE_A(0, 128, 0);
  STAGE_B(0, 0, 0); STAGE_B(0, 1, 0);
  STAGE_B(0, 2, 0); STAGE_B(0, 3, 0);
  STAGE_A(0, 64, 0); STAGE_A(0, 192, 0);
  if (NT > 1) {
    STAGE_A(1, 0, 1); STAGE_A(1, 128, 1);
    STAGE_B(1, 0, 1); STAGE_B(1, 1, 1);
    STAGE_B(1, 2, 1); STAGE_B(1, 3, 1);
    asm volatile("s_waitcnt vmcnt(6)");  // retire tile0's 8
  } else {
    asm volatile("s_waitcnt vmcnt(0)");
  }
  __builtin_amdgcn_s_barrier();

  for (int t = 0; t < NT; ++t) {
    const int cur = t & 1, nxt = cur ^ 1;
    const bool pf1 = (t + 1 < NT);
    const bool pf2 = (t + 2 < NT);

    // ---- P1: read a[0..3] (rows wm+0..63), b[0..1] (sig 0-127);
    //          stage t+1 uA2,uA3 (nxt; region read at P3(t-1)) ----
#pragma unroll
    for (int i = 0; i < 4; ++i) {
      a[i][0] = RD_A(i, 0); a[i][1] = RD_A(i, 1);
    }
#pragma unroll
    for (int j = 0; j < 2; ++j) {
      b[j][0] = RD_B(j, 0); b[j][1] = RD_B(j, 1);
    }
    if (pf1) { STAGE_A(nxt, 64, t + 1); STAGE_A(nxt, 192, t + 1); }
    __builtin_amdgcn_s_barrier();
    __builtin_amdgcn_s_setprio(1);
#pragma unroll
    for (int i = 0; i < 4; ++i)
#pragma unroll
      for (int j = 0; j < 2; ++j) {
        acc[i][j] = __builtin_amdgcn_mfma_f32_16x16x32_f16(a[i][0], b[j][0], acc[i][j], 0, 0, 0);
        acc[i][j] = __builtin_amdgcn_mfma_f32_16x16x32_f16(a[i][1], b[j][1], acc[i][j], 0, 0, 0);
      }
    __builtin_amdgcn_s_setprio(0);
    __builtin_amdgcn_s_barrier();

    // ---- P2: read b[2..3] (sig 128-255); stage t+2 uA0,uA1 (cur; freed P1) ----
#pragma unroll
    for (int j = 2; j < 4; ++j) {
      b[j][0] = RD_B(j, 0); b[j][1] = RD_B(j, 1);
    }
    if (pf2) { STAGE_A(cur, 0, t + 2); STAGE_A(cur, 128, t + 2); }
    __builtin_amdgcn_s_barrier();
    __builtin_amdgcn_s_setprio(1);
#pragma unroll
    for (int i = 0; i < 4; ++i)
#pragma unroll
      for (int j = 2; j < 4; ++j) {
        acc[i][j] = __builtin_amdgcn_mfma_f32_16x16x32_f16(a[i][0], b[j][0], acc[i][j], 0, 0, 0);
        acc[i][j] = __builtin_amdgcn_mfma_f32_16x16x32_f16(a[i][1], b[j][1], acc[i][j], 0, 0, 0);
      }
    __builtin_amdgcn_s_setprio(0);
    __builtin_amdgcn_s_barrier();

    // ---- P3: read a[0..3] <- rows wm+64..127; stage t+2 vB0,vB1 (cur; freed P1) ----
#pragma unroll
    for (int i = 0; i < 4; ++i) {
      a[i][0] = RD_A(i + 4, 0); a[i][1] = RD_A(i + 4, 1);
    }
    if (pf2) { STAGE_B(cur, 0, t + 2); STAGE_B(cur, 1, t + 2); }
    __builtin_amdgcn_s_barrier();
    __builtin_amdgcn_s_setprio(1);
#pragma unroll
    for (int i = 0; i < 4; ++i)
#pragma unroll
      for (int j = 0; j < 2; ++j) {
        acc[i + 4][j] = __builtin_amdgcn_mfma_f32_16x16x32_f16(a[i][0], b[j][0], acc[i + 4][j], 0, 0, 0);
        acc[i + 4][j] = __builtin_amdgcn_mfma_f32_16x16x32_f16(a[i][1], b[j][1], acc[i + 4][j], 0, 0, 0);
      }
    __builtin_amdgcn_s_setprio(0);
    __builtin_amdgcn_s_barrier();

    // ---- P4: stage t+2 vB2,vB3 (cur; freed P2); MFMA; checkpoint ----
    if (pf2) { STAGE_B(cur, 2, t + 2); STAGE_B(cur, 3, t + 2); }
    __builtin_amdgcn_s_barrier();
    __builtin_amdgcn_s_setprio(1);
#pragma unroll
    for (int i = 0; i < 4; ++i)
#pragma unroll
      for (int j = 2; j < 4; ++j) {
        acc[i + 4][j] = __builtin_amdgcn_mfma_f32_16x16x32_f16(a[i][0], b[j][0], acc[i + 4][j], 0, 0, 0);
        acc[i + 4][j] = __builtin_amdgcn_mfma_f32_16x16x32_f16(a[i][1], b[j][1], acc[i + 4][j], 0, 0, 0);
      }
    __builtin_amdgcn_s_setprio(0);
    if (pf2)
      asm volatile("s_waitcnt vmcnt(6)");   // retire tile t+1; t+2's 6 units stay in flight
    else
      asm volatile("s_waitcnt vmcnt(0)");   // drain (last two tiles)
    __builtin_amdgcn_s_barrier();
  }

  // ---- epilogue: bias + store ----
#pragma unroll
  for (int j = 0; j < 4; ++j) {
    const int gc = bn + wn + j * 16 + l16;
    const float* bp = (gc < 2048) ? b0 : (gc < 4096 ? b1 : b2);
    const float bz = bp[gc & 2047];
#pragma unroll
    for (int i = 0; i < 8; ++i) {
#pragma unroll
      for (int r = 0; r < 4; ++r) {
        const int gr = bm + wm + i * 16 + quad * 4 + r;
        float v = acc[i][j][r] + bz;
        if (OUT_F32)
          reinterpret_cast<float*>(Cout)[(size_t)gr * N + gc] = v;
        else
          reinterpret_cast<_Float16*>(Cout)[(size_t)gr * N + gc] = (_Float16)v;
      }
    }
  }
#undef STAGE_A
#undef STAGE_B
#undef RD_A
#undef RD_B
}

// ---------------- RoPE in-place on fused qkv (rows stride 6144) ----------------
__global__ void rope_inplace(_Float16* __restrict__ qkv, int ngroups) {
  int idx = blockIdx.x * blockDim.x + threadIdx.x;
  if (idx >= ngroups) return;
  int m = idx >> 8;
  int g = idx & 255;
  int s = m & 2047;
  const float scale = 0.088388347648318447f;  // 1/sqrt(128)
  size_t base = (size_t)m * 6144 + g * 8;
  half8 qv = *reinterpret_cast<const half8*>(qkv + base);
  half8 kv = *reinterpret_cast<const half8*>(qkv + base + 2048);
  half8 qo, ko;
#pragma unroll
  for (int j = 0; j < 4; ++j) {
    int i = (g * 4 + j) & 63;
    float ang = (float)s * exp2f(-0.2076205059304601f * (float)i);
    float sn, cs;
    __sincosf(ang, &sn, &cs);
    float e = (float)qv[j * 2], o = (float)qv[j * 2 + 1];
    qo[j * 2]     = (_Float16)((e * cs - o * sn) * scale);
    qo[j * 2 + 1] = (_Float16)((o * cs + e * sn) * scale);
    e = (float)kv[j * 2]; o = (float)kv[j * 2 + 1];
    ko[j * 2]     = (_Float16)(e * cs - o * sn);
    ko[j * 2 + 1] = (_Float16)(o * cs + e * sn);
  }
  *reinterpret_cast<half8*>(qkv + base) = qo;
  *reinterpret_cast<half8*>(qkv + base + 2048) = ko;
}

// ---------------- V transpose: qkv v-cols (stride 6144) -> (B,H,dh,S) ----------------
__global__ __launch_bounds__(256) void transpose_v(const _Float16* __restrict__ qkv,
                                                   _Float16* __restrict__ vt) {
  __shared__ _Float16 t[64][72];
  const int s0 = blockIdx.x * 64;
  const int d0 = blockIdx.y * 64;
  const int bh = blockIdx.z;
  const int b = bh >> 4, h = bh & 15;
  const int tid = threadIdx.x;
#pragma unroll
  for (int p = 0; p < 2; ++p) {
    int chunk = p * 256 + tid;
    int r = chunk >> 3, c8 = (chunk & 7) * 8;
    *reinterpret_cast<half8*>(&t[r][c8]) = *reinterpret_cast<const half8*>(
        &qkv[(size_t)(b * 2048 + s0 + r) * 6144 + 4096 + h * 128 + d0 + c8]);
  }
  __syncthreads();
#pragma unroll
  for (int p = 0; p < 2; ++p) {
    int chunk = p * 256 + tid;
    int dr = chunk >> 3, c8 = (chunk & 7) * 8;
    half8 o;
#pragma unroll
    for (int j = 0; j < 8; ++j) o[j] = t[c8 + j][dr];
    *reinterpret_cast<half8*>(&vt[(size_t)(bh * 128 + d0 + dr) * 2048 + s0 + c8]) = o;
  }
}

// ---------------- Flash attention (causal), dbuf LDS K/V ----------------
__global__ __launch_bounds__(256, 2) void attn_kernel(
    const _Float16* __restrict__ QKV,  // (4096, 6144): q|k|v
    const _Float16* __restrict__ VT,   // (32, 128, 2048)
    _Float16* __restrict__ ctx) {      // (4096, 2048)
  constexpr int LD = 6144, S = 2048;
  __shared__ _Float16 Ks[2][8192];
  __shared__ _Float16 Vs[2][8192];
  __shared__ _Float16 P[4][16][80];
  const int bid = blockIdx.x;
  const int bh = bid & 31;
  const int qt = 31 - (bid >> 5);
  const int b = bh >> 4, h = bh & 15;
  const int tid = threadIdx.x;
  const int wv = tid >> 6, lane = tid & 63;
  const int quad = lane >> 4, l16 = lane & 15;
  const int q0 = qt * 64 + wv * 16;

  const _Float16* qp = QKV + (size_t)(b * S + q0 + l16) * LD + h * 128;
  half8 aq[4];
#pragma unroll
  for (int ks = 0; ks < 4; ++ks)
    aq[ks] = *reinterpret_cast<const half8*>(qp + ks * 32 + quad * 8);

  const _Float16* gk[4];
  const _Float16* gv[4];
  int lofs[4];
#pragma unroll
  for (int p = 0; p < 4; ++p) {
    int c = p * 256 + tid;
    int cl16 = c & 15, cqd = (c >> 4) & 3;
    int cks = (c >> 6) & 3, cf = c >> 8;
    gk[p] = QKV + (size_t)(b * S + cf * 16 + cl16) * LD + 2048 + h * 128 + cks * 32 + cqd * 8;
    int ckv = (c >> 6) & 1, ct = c >> 7;
    gv[p] = VT + (size_t)(bh * 128 + ct * 16 + cl16) * S + ckv * 32 + cqd * 8;
    lofs[p] = c * 8;
  }

  f32x4 acc[8];
#pragma unroll
  for (int t = 0; t < 8; ++t) acc[t] = f32x4{0.f, 0.f, 0.f, 0.f};
  f32x4 lacc = f32x4{0.f, 0.f, 0.f, 0.f};
  float m_i[4];
#pragma unroll
  for (int r = 0; r < 4; ++r) m_i[r] = -INFINITY;

  half8 ones;
#pragma unroll
  for (int j = 0; j < 8; ++j) ones[j] = (_Float16)1.0f;

#pragma unroll
  for (int p = 0; p < 4; ++p) gl_lds16(gk[p], &Ks[0][lofs[p]]);
#pragma unroll
  for (int p = 0; p < 4; ++p) gl_lds16(gv[p], &Vs[0][lofs[p]]);

  for (int j = 0; j <= qt; ++j) {
    __syncthreads();
    const int cur = j & 1;
    if (j < qt) {
      const size_t ko = (size_t)(j + 1) * 64 * LD;
      const int vo = (j + 1) * 64;
#pragma unroll
      for (int p = 0; p < 4; ++p) gl_lds16(gk[p] + ko, &Ks[cur ^ 1][lofs[p]]);
#pragma unroll
      for (int p = 0; p < 4; ++p) gl_lds16(gv[p] + vo, &Vs[cur ^ 1][lofs[p]]);
    }
    f32x4 sf[4];
#pragma unroll
    for (int f = 0; f < 4; ++f) sf[f] = f32x4{0.f, 0.f, 0.f, 0.f};
#pragma unroll
    for (int f = 0; f < 4; ++f)
#pragma unroll
      for (int ks = 0; ks < 4; ++ks) {
        half8 bk = *reinterpret_cast<const half8*>(&Ks[cur][((f * 4 + ks) * 4 + quad) * 128 + l16 * 8]);
        sf[f] = __builtin_amdgcn_mfma_f32_16x16x32_f16(aq[ks], bk, sf[f], 0, 0, 0);
      }
    if (j == qt) {
      const int key0 = j * 64;
#pragma unroll
      for (int f = 0; f < 4; ++f) {
        const int key = key0 + f * 16 + l16;
#pragma unroll
        for (int r = 0; r < 4; ++r) {
          const int row = q0 + quad * 4 + r;
          sf[f][r] = (key <= row) ? sf[f][r] : -1e30f;
        }
      }
    }
    float alpha[4];
#pragma unroll
    for (int r = 0; r < 4; ++r) {
      float tm = fmaxf(fmaxf(sf[0][r], sf[1][r]), fmaxf(sf[2][r], sf[3][r]));
      tm = fmaxf(tm, __shfl_xor(tm, 1));
      tm = fmaxf(tm, __shfl_xor(tm, 2));
      tm = fmaxf(tm, __shfl_xor(tm, 4));
      tm = fmaxf(tm, __shfl_xor(tm, 8));
      const float mn = fmaxf(m_i[r], tm);
      alpha[r] = __expf(m_i[r] - mn);
      m_i[r] = mn;
    }
#pragma unroll
    for (int f = 0; f < 4; ++f)
#pragma unroll
      for (int r = 0; r < 4; ++r)
        P[wv][quad * 4 + r][f * 16 + l16] = (_Float16)__expf(sf[f][r] - m_i[r]);
    half8 pa0 = *reinterpret_cast<const half8*>(&P[wv][l16][quad * 8]);
    half8 pa1 = *reinterpret_cast<const half8*>(&P[wv][l16][32 + quad * 8]);
#pragma unroll
    for (int t = 0; t < 8; ++t)
#pragma unroll
      for (int r = 0; r < 4; ++r) acc[t][r] *= alpha[r];
#pragma unroll
    for (int r = 0; r < 4; ++r) lacc[r] *= alpha[r];
#pragma unroll
    for (int t = 0; t < 8; ++t) {
      half8 bv0 = *reinterpret_cast<const half8*>(&Vs[cur][((t * 2 + 0) * 4 + quad) * 128 + l16 * 8]);
      half8 bv1 = *reinterpret_cast<const half8*>(&Vs[cur][((t * 2 + 1) * 4 + quad) * 128 + l16 * 8]);
      acc[t] = __builtin_amdgcn_mfma_f32_16x16x32_f16(pa0, bv0, acc[t], 0, 0, 0);
      acc[t] = __builtin_amdgcn_mfma_f32_16x16x32_f16(pa1, bv1, acc[t], 0, 0, 0);
    }
    lacc = __builtin_amdgcn_mfma_f32_16x16x32_f16(pa0, ones, lacc, 0, 0, 0);
    lacc = __builtin_amdgcn_mfma_f32_16x16x32_f16(pa1, ones, lacc, 0, 0, 0);
  }

  float inv[4];
#pragma unroll
  for (int r = 0; r < 4; ++r) inv[r] = 1.0f / lacc[r];
#pragma unroll
  for (int t = 0; t < 8; ++t)
#pragma unroll
    for (int r = 0; r < 4; ++r)
      ctx[(size_t)(b * S + q0 + quad * 4 + r) * 2048 + h * 128 + t * 16 + l16] =
          (_Float16)(acc[t][r] * inv[r]);
}

// ---------------- launcher ----------------
extern "C" void kernel_launch(void* const* d_in, const int* in_sizes, int n_in,
                              void* d_out, int out_size, void* d_ws, size_t ws_size,
                              hipStream_t stream) {
  const float* x  = (const float*)d_in[0];
  const float* wq = (const float*)d_in[1];
  const float* bq = (const float*)d_in[2];
  const float* wk = (const float*)d_in[3];
  const float* bk = (const float*)d_in[4];
  const float* wv = (const float*)d_in[5];
  const float* bv = (const float*)d_in[6];
  const float* wo = (const float*)d_in[7];
  const float* bo = (const float*)d_in[8];

  _Float16* W      = (_Float16*)d_ws;
  _Float16* xh     = W;                  // 16 MB (4096,2048)
  _Float16* wqkvh  = xh + 8388608;       // 24 MB (6144,2048) contiguous wq|wk|wv
  _Float16* woh    = wqkvh + 12582912;   // 8 MB  (2048,2048)
  _Float16* qkvlin = woh + 4194304;      // 48 MB (4096,6144)
  _Float16* vT     = xh;                 // reuse: x dead after QKV gemm
  _Float16* ctx    = wqkvh;              // reuse: wqkv dead after QKV gemm

  cast_f32_f16<<<8192, 256, 0, stream>>>(x, xh, 2097152);
  cast_w<<<dim3(4096, 4), 256, 0, stream>>>(wq, wk, wv, wo, wqkvh);

  // fused QKV gemm: (4096,2048) x (6144,2048)^T -> (4096,6144)
  gemm_bt256<false><<<dim3(24, 16), 512, 0, stream>>>(xh, wqkvh, bq, bk, bv, qkvlin,
                                                      4096, 6144, 2048);

  rope_inplace<<<4096, 256, 0, stream>>>(qkvlin, 1048576);
  transpose_v<<<dim3(32, 2, 32), 256, 0, stream>>>(qkvlin, vT);
  attn_kernel<<<1024, 256, 0, stream>>>(qkvlin, vT, ctx);

  // output gemm: (4096,2048) x (2048,2048)^T -> fp32 out
  gemm_bt256<true><<<dim3(8, 16), 512, 0, stream>>>(ctx, woh, bo, bo, bo, (float*)d_out,
                                                    4096, 2048, 2048);
}